// Round 1
// baseline (13.259 us; speedup 1.0000x reference)
//
#include <hip/hip_runtime.h>

// CenterLoss: loss = mean_i clamp(||x_i - c_{l_i}||^2, 1e-12, 1e12) + (C_OUT-1)*1e-12
// (the masked-then-clamped zeros contribute exactly (c_out-1)*1e-12 per row)

#define BS_N 8192
#define C_OUT_N 50000
#define D_N 64

#define NBLOCKS 2048
#define NTHREADS 256  // 4 waves/block -> 8192 waves total = 1 wave per row

__global__ void center_loss_partial(const float* __restrict__ x,
                                    const int* __restrict__ labels,
                                    const float* __restrict__ centers,
                                    float* __restrict__ partials) {
    const int gtid   = blockIdx.x * blockDim.x + threadIdx.x;
    const int wave   = gtid >> 6;                 // global wave id
    const int lane   = threadIdx.x & 63;          // lane = dim (D == 64)
    const int nwaves = (gridDim.x * blockDim.x) >> 6;

    float acc = 0.0f;
    for (int row = wave; row < BS_N; row += nwaves) {
        const int lbl = labels[row];
        const float xv = x[row * D_N + lane];
        const float cv = centers[lbl * D_N + lane];
        const float d  = xv - cv;
        float v = d * d;
        // 64-lane wave reduction
        #pragma unroll
        for (int off = 32; off > 0; off >>= 1)
            v += __shfl_down(v, off, 64);
        if (lane == 0) {
            v = fminf(fmaxf(v, 1e-12f), 1e12f);
            acc += v;
        }
    }

    __shared__ float smem[NTHREADS / 64];
    const int wib = threadIdx.x >> 6;
    if (lane == 0) smem[wib] = acc;
    __syncthreads();
    if (threadIdx.x == 0) {
        float s = 0.0f;
        #pragma unroll
        for (int i = 0; i < NTHREADS / 64; ++i) s += smem[i];
        partials[blockIdx.x] = s;
    }
}

__global__ void center_loss_final(const float* __restrict__ partials,
                                  float* __restrict__ out) {
    float v = 0.0f;
    for (int i = threadIdx.x; i < NBLOCKS; i += blockDim.x) v += partials[i];
    #pragma unroll
    for (int off = 32; off > 0; off >>= 1)
        v += __shfl_down(v, off, 64);

    __shared__ float smem[NTHREADS / 64];
    const int lane = threadIdx.x & 63;
    const int wib  = threadIdx.x >> 6;
    if (lane == 0) smem[wib] = v;
    __syncthreads();
    if (threadIdx.x == 0) {
        float s = 0.0f;
        #pragma unroll
        for (int i = 0; i < NTHREADS / 64; ++i) s += smem[i];
        double loss = (double)s / (double)BS_N
                    + (double)(C_OUT_N - 1) * 1e-12;  // masked zeros clamped to 1e-12
        out[0] = (float)loss;
    }
}

extern "C" void kernel_launch(void* const* d_in, const int* in_sizes, int n_in,
                              void* d_out, int out_size, void* d_ws, size_t ws_size,
                              hipStream_t stream) {
    const float* x       = (const float*)d_in[0];
    const int*   labels  = (const int*)d_in[1];
    const float* centers = (const float*)d_in[2];
    float*       out     = (float*)d_out;
    float*       partials = (float*)d_ws;  // NBLOCKS floats

    center_loss_partial<<<NBLOCKS, NTHREADS, 0, stream>>>(x, labels, centers, partials);
    center_loss_final<<<1, NTHREADS, 0, stream>>>(partials, out);
}